// Round 7
// baseline (256.722 us; speedup 1.0000x reference)
//
#include <hip/hip_runtime.h>
#include <hip/hip_bf16.h>
#include <math.h>

#define N_BATCH 8
#define WDIM 64
#define TDIM 8192
#define KBINS 2048
#define NROWS (N_BATCH * TDIM)          // 65536
#define XSIZE (N_BATCH * WDIM * TDIM)   // 4194304
#define XL_OFF 0
#define XD_OFF NROWS
#define SCAL_OFF (NROWS + XSIZE)

#define MT 64                           // rows per block
#define XST 72                          // bf16 LDS x row stride
#define TAU 0.05f
#define MAXFLAG 8192
#define NBLK (NROWS / MT)               // 1024

// ws layout (bytes):
//   0       : float k2[KBINS]            (8192)
//   8192    : int   flag_cnt
//   8256    : int   flags[MAXFLAG]       (32768)
//   41024   : u64   slots[MAXFLAG]       (65536)
//   106560  : float part[4][NBLK]        (16384)
//   122944  : char  kfrag[128*4096]      (524288)
//   647296  : float kT[64][2048]         (524288, optional)
#define WS_K2_OFF   0
#define WS_CNT_OFF  8192
#define WS_FLAG_OFF 8256
#define WS_SLOT_OFF 41024
#define WS_PART_OFF 106560
#define WS_KF_OFF   122944
#define WS_KT_OFF   647296
#define WS_KT_END   (WS_KT_OFF + (size_t)WDIM * KBINS * 4)

typedef __attribute__((ext_vector_type(8))) short bf16x8;
typedef __attribute__((ext_vector_type(4))) float f32x4;
typedef unsigned long long u64;

static __device__ __forceinline__ short f2bf(float v) {
  __hip_bfloat16 b = __float2bfloat16(v);
  return *reinterpret_cast<short*>(&b);
}
static __device__ __forceinline__ float bf2f(short s) {
  unsigned int u = ((unsigned int)(unsigned short)s) << 16;
  return __uint_as_float(u);
}

#define GLOAD_LDS(gsrc, ldst)                                            \
  __builtin_amdgcn_global_load_lds(                                      \
      (const __attribute__((address_space(1))) unsigned int*)(gsrc),     \
      (__attribute__((address_space(3))) unsigned int*)(ldst), 16, 0, 0)

// s_waitcnt immediates (gfx9): vmcnt[3:0] bits3:0 | expcnt bits6:4 |
// lgkmcnt bits11:8 | vmcnt[5:4] bits15:14
#define WAIT_VM8 0x0F78
#define WAIT_VM0 0x0F70
#define SBAR() asm volatile("s_barrier" ::: "memory")

// prep: 1 block per 16-code tile. np-bit-exact k2 + fragment-ordered split-bf16
// codebook + optional kT transpose + ws init.
__global__ void prep_kernel(const float* __restrict__ kg, float* __restrict__ k2,
                            char* __restrict__ kfrag, float* __restrict__ kT,
                            int* __restrict__ cnt, u64* __restrict__ slots) {
  __shared__ float skc[16 * 65];
  const int tid  = threadIdx.x;
  const int tile = blockIdx.x;           // 0..127
  const int c0   = tile * 16;
  if (tile == 0 && tid == 0) *cnt = 0;
  if (tid < 64) slots[tile * 64 + tid] = ~0ULL;
  {
    const float4* g4 = (const float4*)(kg + (size_t)c0 * WDIM);
    int code = tid >> 4, w = (tid & 15) * 4;
    *(float4*)&skc[code * 65 + w] = g4[tid];
  }
  __syncthreads();
  if (tid < 16) {   // np-bit-exact k2 (8-accumulator pairwise)
    const float* kr = &skc[tid * 65];
    float r[8];
#pragma unroll
    for (int l = 0; l < 8; ++l) r[l] = __fmul_rn(kr[l], kr[l]);
    for (int i = 8; i < WDIM; i += 8) {
#pragma unroll
      for (int l = 0; l < 8; ++l)
        r[l] = __fadd_rn(r[l], __fmul_rn(kr[i + l], kr[i + l]));
    }
    k2[c0 + tid] = __fadd_rn(__fadd_rn(__fadd_rn(r[0], r[1]), __fadd_rn(r[2], r[3])),
                             __fadd_rn(__fadd_rn(r[4], r[5]), __fadd_rn(r[6], r[7])));
  }
  if (kT) {   // transposed copy for coalesced recheck reads (bit-exact values)
    const int code = tid & 15;
#pragma unroll
    for (int j = 0; j < 4; ++j) {
      int w = (tid >> 4) + 16 * j;
      kT[(size_t)w * KBINS + c0 + code] = skc[code * 65 + w];
    }
  }
  {
    const int sub  = tid >> 6;           // 0..3
    const int lane = tid & 63;
    const int lcol = lane & 15;
    const int quad = lane >> 4;
    const float* src = &skc[lcol * 65 + (sub & 1) * 32 + quad * 8];
    const bool lo = (sub >= 2);
    short tmp[8];
#pragma unroll
    for (int i = 0; i < 8; ++i) {
      float v = src[i];
      short h = f2bf(v);
      tmp[i] = lo ? f2bf(v - bf2f(h)) : h;
    }
    char* dst = kfrag + (size_t)tile * 4096 + sub * 1024 + lane * 16;
    *(bf16x8*)dst = *(const bf16x8*)tmp;
  }
}

// main: split-bf16 MFMA scan, 256 thr = 4 waves x 16 rows, ALL 128 tiles.
// PAIR-PIPELINED ring: 6 slots = 3 pairs x 8192B. Each barrier-step consumes
// 2 tiles (two INDEPENDENT 6-MFMA chains p/q -> 2x ILP) and wave0 prefetches
// the pair 2 steps ahead into the pair-slot consumed in the PREVIOUS barrier
// interval (same safety argument as the proven 3-slot ring, scaled x2; wait
// literal becomes vmcnt(8) = one 8-gld pair in flight). 64 barriers (was 128).
// LDS: ring 24576 + k2f 8192 + smalls = 33408 -> 4 blocks/CU (= grid cap).
__launch_bounds__(256, 4)
__global__ void vq_mono(const float* __restrict__ x,
                        const float* __restrict__ kg,
                        const float* __restrict__ k2g,
                        const char* __restrict__ kfrag,
                        float* __restrict__ out,
                        float* __restrict__ part,
                        int* __restrict__ flag_cnt,
                        int* __restrict__ flags) {
  __shared__ __align__(16) char smem[33408];
  char*  kbuf = smem;                      // 3 pairs x 8192 ring (24576)
  float* k2f  = (float*)(smem + 24576);    // k2[2048] (8192, ends 32768)
  int*   sIdx      = (int*)  (smem + 32768);  // 64 ints
  float* sPair     = (float*)(smem + 33024);  // 16 floats
  int*   sFlagCnt  = (int*)  (smem + 33088);
  int*   sFlagBase = (int*)  (smem + 33092);
  int*   sFlagList = (int*)  (smem + 33096);  // 64 ints
  // prologue overlay of ring (dead before first ring write, barrier-protected):
  short* sxh = (short*)smem;               // [64][72] bf16 hi (9216)
  short* sxl = (short*)(smem + 9216);      // [64][72] bf16 lo (ends 18432)
  // epilogue overlay of ring:
  float* kd  = (float*)smem;               // [64][68] f32 (17408)

  const int tid  = threadIdx.x;
  const int blk  = blockIdx.x;
  const int row0 = blk * MT;
  const int n    = row0 >> 13;
  const int t0   = row0 & (TDIM - 1);

  // ---- stage x tile -> split bf16; k2 -> LDS (disjoint region); partials ----
  const int r  = tid & 63;
  const int wh = tid >> 6;
  float x2p = 0.f, sxp = 0.f;
  const float* xb = x + (size_t)n * WDIM * TDIM + t0 + r;
#pragma unroll 8
  for (int i = 0; i < 16; ++i) {
    int w = 4 * i + wh;
    float v = xb[(size_t)w * TDIM];
    x2p = fmaf(v, v, x2p);
    sxp += v;
    short h = f2bf(v);
    sxh[r * XST + w] = h;
    sxl[r * XST + w] = f2bf(v - bf2f(h));
  }
  {
    const float4* k24 = (const float4*)k2g;
    *(float4*)&k2f[tid * 8]     = k24[tid * 2];
    *(float4*)&k2f[tid * 8 + 4] = k24[tid * 2 + 1];
  }
  __syncthreads();

  // ---- A fragments (each wave: one 16-row subtile) ----
  const int wave = tid >> 6;
  const int lane = tid & 63;
  const int lcol = lane & 15;
  const int quad = lane >> 4;
  const int rA = wave * 16 + lcol;
  bf16x8 ah0 = *(const bf16x8*)&sxh[rA * XST + 0  + quad * 8];
  bf16x8 ah1 = *(const bf16x8*)&sxh[rA * XST + 32 + quad * 8];
  bf16x8 al0 = *(const bf16x8*)&sxl[rA * XST + 0  + quad * 8];
  bf16x8 al1 = *(const bf16x8*)&sxl[rA * XST + 32 + quad * 8];
  __syncthreads();   // all waves done with sxh/sxl -> ring writes may land

  float bd[4], b2[4];
  int   bi[4];
#pragma unroll
  for (int i = 0; i < 4; ++i) { bd[i] = 3.0e38f; b2[i] = 3.0e38f; bi[i] = 0; }

  const char* kfg = kfrag;

  // issue async stage of tiles C,C+1 into pair-slot P (8 x 1KB glds)
#define VQ_ISSUE2(C, P)                                                      \
  {                                                                          \
    const char* s = kfg + (size_t)(C) * 4096 + (lane << 4);                  \
    char* d = kbuf + (P) * 8192;                                             \
    GLOAD_LDS(s, d);                                                         \
    GLOAD_LDS(s + 1024, d + 1024);                                           \
    GLOAD_LDS(s + 2048, d + 2048);                                           \
    GLOAD_LDS(s + 3072, d + 3072);                                           \
    GLOAD_LDS(s + 4096, d + 4096);                                           \
    GLOAD_LDS(s + 5120, d + 5120);                                           \
    GLOAD_LDS(s + 6144, d + 6144);                                           \
    GLOAD_LDS(s + 7168, d + 7168);                                           \
  }

  // prologue: wave0 primes pairs 0 (tiles 0,1 -> slot0) and 1 (tiles 2,3 -> slot1)
  if (wave == 0) {
    VQ_ISSUE2(0, 0)
    VQ_ISSUE2(2, 1)
  }

  // one 2-tile step: consume pair at slot P (tiles C,C+1); wave0 prefetches
  // tiles C+4,C+5 into slot IP (the pair consumed last step).
#define VQ_STEP2(C, P, IP, WAITIMM, DOISS)                                   \
  {                                                                          \
    if (wave == 0) __builtin_amdgcn_s_waitcnt(WAITIMM);                      \
    SBAR();                                                                  \
    const char* ta = kbuf + (P) * 8192;                                      \
    bf16x8 xh0 = *(const bf16x8*)(ta + 0    + (lane << 4));                  \
    bf16x8 xh1 = *(const bf16x8*)(ta + 1024 + (lane << 4));                  \
    bf16x8 xl0 = *(const bf16x8*)(ta + 2048 + (lane << 4));                  \
    bf16x8 xl1 = *(const bf16x8*)(ta + 3072 + (lane << 4));                  \
    bf16x8 yh0 = *(const bf16x8*)(ta + 4096 + (lane << 4));                  \
    bf16x8 yh1 = *(const bf16x8*)(ta + 5120 + (lane << 4));                  \
    bf16x8 yl0 = *(const bf16x8*)(ta + 6144 + (lane << 4));                  \
    bf16x8 yl1 = *(const bf16x8*)(ta + 7168 + (lane << 4));                  \
    float k2a = k2f[(C) * 16 + lcol];                                        \
    float k2b = k2f[(C) * 16 + 16 + lcol];                                   \
    if (wave == 0 && (DOISS)) { VQ_ISSUE2((C) + 4, IP) }                     \
    f32x4 p = {0.f, 0.f, 0.f, 0.f};                                          \
    f32x4 q = {0.f, 0.f, 0.f, 0.f};                                          \
    p = __builtin_amdgcn_mfma_f32_16x16x32_bf16(ah0, xh0, p, 0, 0, 0);       \
    q = __builtin_amdgcn_mfma_f32_16x16x32_bf16(ah0, yh0, q, 0, 0, 0);       \
    p = __builtin_amdgcn_mfma_f32_16x16x32_bf16(ah1, xh1, p, 0, 0, 0);       \
    q = __builtin_amdgcn_mfma_f32_16x16x32_bf16(ah1, yh1, q, 0, 0, 0);       \
    p = __builtin_amdgcn_mfma_f32_16x16x32_bf16(ah0, xl0, p, 0, 0, 0);       \
    q = __builtin_amdgcn_mfma_f32_16x16x32_bf16(ah0, yl0, q, 0, 0, 0);       \
    p = __builtin_amdgcn_mfma_f32_16x16x32_bf16(ah1, xl1, p, 0, 0, 0);       \
    q = __builtin_amdgcn_mfma_f32_16x16x32_bf16(ah1, yl1, q, 0, 0, 0);       \
    p = __builtin_amdgcn_mfma_f32_16x16x32_bf16(al0, xh0, p, 0, 0, 0);       \
    q = __builtin_amdgcn_mfma_f32_16x16x32_bf16(al0, yh0, q, 0, 0, 0);       \
    p = __builtin_amdgcn_mfma_f32_16x16x32_bf16(al1, xh1, p, 0, 0, 0);       \
    q = __builtin_amdgcn_mfma_f32_16x16x32_bf16(al1, yh1, q, 0, 0, 0);       \
    const int codeA = (C) * 16 + lcol;                                       \
    _Pragma("unroll")                                                        \
    for (int i = 0; i < 4; ++i) {                                            \
      float d0 = fmaf(-2.f, p[i], k2a);                                      \
      float nb2 = __builtin_amdgcn_fmed3f(bd[i], d0, b2[i]);                 \
      bool lt0 = d0 < bd[i];                                                 \
      bd[i] = lt0 ? d0 : bd[i];                                              \
      bi[i] = lt0 ? codeA : bi[i];                                           \
      b2[i] = nb2;                                                           \
      float d1 = fmaf(-2.f, q[i], k2b);                                      \
      float nb2b = __builtin_amdgcn_fmed3f(bd[i], d1, b2[i]);                \
      bool lt1 = d1 < bd[i];                                                 \
      bd[i] = lt1 ? d1 : bd[i];                                              \
      bi[i] = lt1 ? (codeA + 16) : bi[i];                                    \
      b2[i] = nb2b;                                                          \
    }                                                                        \
  }

  for (int c = 0; c < 120; c += 6) {
    VQ_STEP2(c,     0, 2, WAIT_VM8, 1)
    VQ_STEP2(c + 2, 1, 0, WAIT_VM8, 1)
    VQ_STEP2(c + 4, 2, 1, WAIT_VM8, 1)
  }
  VQ_STEP2(120, 0, 2, WAIT_VM8, 1)
  VQ_STEP2(122, 1, 0, WAIT_VM8, 1)
  VQ_STEP2(124, 2, 1, WAIT_VM8, 0)
  VQ_STEP2(126, 0, 2, WAIT_VM0, 0)
#undef VQ_STEP2
#undef VQ_ISSUE2

  // ---- reduce across the 16 col-classes (registers only) ----
#pragma unroll
  for (int m = 1; m < 16; m <<= 1) {
#pragma unroll
    for (int i = 0; i < 4; ++i) {
      float od  = __shfl_xor(bd[i], m, 64);
      float od2 = __shfl_xor(b2[i], m, 64);
      int   oi  = __shfl_xor(bi[i], m, 64);
      float nb2 = fminf(fminf(b2[i], od2), fmaxf(bd[i], od));
      bool take = (od < bd[i]) || (od == bd[i] && oi < bi[i]);
      bd[i] = take ? od : bd[i];
      bi[i] = take ? oi : bi[i];
      b2[i] = nb2;
    }
  }

  __syncthreads();                 // loop LDS regions now dead for all waves
  if (tid == 0) *sFlagCnt = 0;
  __syncthreads();

  float fit_p = 0.f;
  if (lcol == 0) {
#pragma unroll
    for (int i = 0; i < 4; ++i) {
      int rloc = wave * 16 + quad * 4 + i;
      int rowg = row0 + rloc;
      out[XL_OFF + rowg] = (float)bi[i];
      sIdx[rloc] = bi[i];
      fit_p += bd[i];
      if (b2[i] - bd[i] < TAU) {
        int slot = atomicAdd(sFlagCnt, 1);
        sFlagList[slot] = rowg;
      }
    }
  }
  __syncthreads();

  int nloc = *sFlagCnt;
  if (tid == 0 && nloc > 0) *sFlagBase = atomicAdd(flag_cnt, nloc);
  __syncthreads();
  if (tid < nloc) {
    int gs = *sFlagBase + tid;
    if (gs < MAXFLAG) flags[gs] = sFlagList[tid];
  }

  // ---- gather chosen code rows (fp32) into LDS (ring overlay, now dead) ----
  {
    int rr = tid >> 2, q4 = tid & 3;
    const float4* kr4 = (const float4*)(kg + (size_t)sIdx[rr] * WDIM) + q4 * 4;
    float4* dst = (float4*)&kd[rr * 68 + q4 * 16];
#pragma unroll
    for (int j = 0; j < 4; ++j) dst[j] = kr4[j];
  }
  __syncthreads();

  // ---- x_d transposed write + commit ----
  float commit_p = 0.f;
  float* xdb = out + XD_OFF + (size_t)n * WDIM * TDIM + t0 + r;
#pragma unroll 8
  for (int i = 0; i < 16; ++i) {
    int w = 4 * i + wh;
    float xvv = xb[(size_t)w * TDIM];
    float kvv = kd[r * 68 + w];
    float df = kvv - xvv;
    commit_p = fmaf(df, df, commit_p);
    xdb[(size_t)w * TDIM] = kvv;
  }

  // ---- block scalar partials ----
  float v0 = sxp, v1 = x2p, v2 = commit_p, v3 = fit_p;
#pragma unroll
  for (int off = 32; off > 0; off >>= 1) {
    v0 += __shfl_down(v0, off, 64);
    v1 += __shfl_down(v1, off, 64);
    v2 += __shfl_down(v2, off, 64);
    v3 += __shfl_down(v3, off, 64);
  }
  if (lane == 0) {
    sPair[wave * 4 + 0] = v0;
    sPair[wave * 4 + 1] = v1;
    sPair[wave * 4 + 2] = v2;
    sPair[wave * 4 + 3] = v3;
  }
  __syncthreads();
  if (tid == 0) {
    float x2sum = sPair[1] + sPair[5] + sPair[9] + sPair[13];
    part[0 * NBLK + blk] = sPair[0] + sPair[4] + sPair[8] + sPair[12];
    part[1 * NBLK + blk] = x2sum;
    part[2 * NBLK + blk] = sPair[2] + sPair[6] + sPair[10] + sPair[14];
    part[3 * NBLK + blk] = (sPair[3] + sPair[7] + sPair[11] + sPair[15]) + x2sum;
  }
}

// recheck pass 1: ONE BLOCK PER FLAGGED ROW; 8 segments as an inner
// NON-unrolled loop (R4's spill came from the full unroll; arithmetic chain
// per (row,segment) is byte-identical to the proven bit-exact version).
// x row + serial x2 computed ONCE per row (was 8x).
__launch_bounds__(256, 4)
__global__ void recheck_scan(const float* __restrict__ x,
                             const float* __restrict__ kg,
                             const float* __restrict__ kT,
                             const float* __restrict__ k2g,
                             const int* __restrict__ flag_cnt,
                             const int* __restrict__ flags,
                             u64* __restrict__ slots) {
  __shared__ float sx[WDIM];
  __shared__ float sx2s;
  __shared__ u64 swm[4];
  const int tid  = threadIdx.x;
  const int lane = tid & 63;
  const int wv   = tid >> 6;
  int nf = *flag_cnt;
  if (nf > MAXFLAG) nf = MAXFLAG;

  for (int fi = blockIdx.x; fi < nf; fi += 1024) {
    const int row = flags[fi];
    const int n = row >> 13;
    const int t = row & (TDIM - 1);
    if (tid < WDIM) sx[tid] = x[(size_t)n * WDIM * TDIM + (size_t)tid * TDIM + t];
    __syncthreads();
    if (tid == 0) {   // np-pairwise x2 (bit-exact chain)
      float r8[8];
#pragma unroll
      for (int l = 0; l < 8; ++l) r8[l] = __fmul_rn(sx[l], sx[l]);
      for (int i = 8; i < WDIM; i += 8) {
#pragma unroll
        for (int l = 0; l < 8; ++l)
          r8[l] = __fadd_rn(r8[l], __fmul_rn(sx[i + l], sx[i + l]));
      }
      sx2s = __fadd_rn(__fadd_rn(__fadd_rn(r8[0], r8[1]), __fadd_rn(r8[2], r8[3])),
                       __fadd_rn(__fadd_rn(r8[4], r8[5]), __fadd_rn(r8[6], r8[7])));
    }
    __syncthreads();

    u64 best = ~0ULL;
#pragma unroll 1
    for (int s = 0; s < 8; ++s) {
      const int j = s * 256 + tid;
      float c = 0.f;
      if (kT) {
#pragma unroll
        for (int w = 0; w < WDIM; ++w)
          c = __fmaf_rn(sx[w], kT[(size_t)w * KBINS + j], c);
      } else {
        const float* kr = kg + (size_t)j * WDIM;
#pragma unroll
        for (int w = 0; w < WDIM; ++w)
          c = __fmaf_rn(sx[w], kr[w], c);
      }
      float d = __fadd_rn(__fsub_rn(sx2s, __fmul_rn(2.0f, c)), k2g[j]);
      u64 key = ((u64)__float_as_uint(d) << 32) | (unsigned)j;
      best = (key < best) ? key : best;
    }
#pragma unroll
    for (int off = 32; off > 0; off >>= 1) {
      u64 o = __shfl_down((unsigned long long)best, off, 64);
      if (o < best) best = o;
    }
    if (lane == 0) swm[wv] = best;
    __syncthreads();
    if (tid == 0) {
      u64 b = swm[0];
#pragma unroll
      for (int k = 1; k < 4; ++k) b = (swm[k] < b) ? swm[k] : b;
      atomicMin(&slots[fi], b);
    }
    __syncthreads();
  }
}

// recheck pass 2: persistent write-back.
__global__ void recheck_write(const float* __restrict__ kg,
                              const int* __restrict__ flag_cnt,
                              const int* __restrict__ flags,
                              const u64* __restrict__ slots,
                              float* __restrict__ out) {
  int nf = *flag_cnt;
  if (nf > MAXFLAG) nf = MAXFLAG;
  const int w = threadIdx.x;
  for (int fi = blockIdx.x; fi < nf; fi += 256) {
    const int row = flags[fi];
    const int n = row >> 13;
    const int t = row & (TDIM - 1);
    const int j = (int)(slots[fi] & 0xFFFFFFFFULL);
    if (w == 0) out[XL_OFF + row] = (float)j;
    out[XD_OFF + (size_t)n * WDIM * TDIM + (size_t)w * TDIM + t] = kg[(size_t)j * WDIM + w];
  }
}

// finalize: sum per-block partials (fp64) + emit the 3 scalars.
__global__ void finalize_kernel(const float* __restrict__ part, float* __restrict__ out) {
  __shared__ double sred[4][64];
  const int tid = threadIdx.x;     // 256
  const int lane = tid & 63;
  const int wv = tid >> 6;
  double a[4] = {0.0, 0.0, 0.0, 0.0};
  for (int i = tid; i < NBLK; i += 256) {
#pragma unroll
    for (int q = 0; q < 4; ++q) a[q] += (double)part[q * NBLK + i];
  }
#pragma unroll
  for (int off = 32; off > 0; off >>= 1) {
#pragma unroll
    for (int q = 0; q < 4; ++q)
      a[q] += __shfl_down(a[q], off, 64);
  }
  if (lane == 0) {
#pragma unroll
    for (int q = 0; q < 4; ++q) sred[q][wv] = a[q];
  }
  __syncthreads();
  if (tid == 0) {
    double s0 = 0, s1 = 0, s2 = 0, s3 = 0;
#pragma unroll
    for (int wv2 = 0; wv2 < 4; ++wv2) {
      s0 += sred[0][wv2]; s1 += sred[1][wv2];
      s2 += sred[2][wv2]; s3 += sred[3][wv2];
    }
    double size = (double)XSIZE;
    double commit = s2 / size;
    double fit = s3 / (double)NROWS;
    double mean = s0 / size;
    double var = s1 / size - mean * mean;
    if (var < 0.0) var = 0.0;
    out[SCAL_OFF + 0] = (float)commit;
    out[SCAL_OFF + 1] = (float)fit;
    out[SCAL_OFF + 2] = (float)sqrt(var);
  }
}

extern "C" void kernel_launch(void* const* d_in, const int* in_sizes, int n_in,
                              void* d_out, int out_size, void* d_ws, size_t ws_size,
                              hipStream_t stream) {
  const float* x = (const float*)d_in[0];
  const float* kg = (const float*)d_in[1];
  float* out = (float*)d_out;
  float* k2   = (float*)((char*)d_ws + WS_K2_OFF);
  int* cnt    = (int*)((char*)d_ws + WS_CNT_OFF);
  int* flags  = (int*)((char*)d_ws + WS_FLAG_OFF);
  u64* slots  = (u64*)((char*)d_ws + WS_SLOT_OFF);
  float* part = (float*)((char*)d_ws + WS_PART_OFF);
  char* kfrag = (char*)d_ws + WS_KF_OFF;
  float* kT   = (ws_size >= WS_KT_END) ? (float*)((char*)d_ws + WS_KT_OFF) : nullptr;

  hipLaunchKernelGGL(prep_kernel, dim3(KBINS / 16), dim3(256), 0, stream,
                     kg, k2, kfrag, kT, cnt, slots);
  hipLaunchKernelGGL(vq_mono, dim3(NBLK), dim3(256), 0, stream,
                     x, kg, k2, kfrag, out, part, cnt, flags);
  hipLaunchKernelGGL(recheck_scan, dim3(1024), dim3(256), 0, stream,
                     x, kg, kT, k2, cnt, flags, slots);
  hipLaunchKernelGGL(recheck_write, dim3(256), dim3(WDIM), 0, stream,
                     kg, cnt, flags, slots, out);
  hipLaunchKernelGGL(finalize_kernel, dim3(1), dim3(256), 0, stream, part, out);
}

// Round 8
// 228.361 us; speedup vs baseline: 1.1242x; 1.1242x over previous
//
#include <hip/hip_runtime.h>
#include <hip/hip_bf16.h>
#include <math.h>

#define N_BATCH 8
#define WDIM 64
#define TDIM 8192
#define KBINS 2048
#define NROWS (N_BATCH * TDIM)          // 65536
#define XSIZE (N_BATCH * WDIM * TDIM)   // 4194304
#define XL_OFF 0
#define XD_OFF NROWS
#define SCAL_OFF (NROWS + XSIZE)

#define MT 64                           // rows per block
#define XST 72                          // bf16 LDS x row stride
#define TAU 0.05f
#define MAXFLAG 8192
#define NBLK (NROWS / MT)               // 1024
#define RPB 16                          // recheck rows per block

// ws layout (bytes):
//   0       : float k2[KBINS]            (8192)
//   8192    : int   flag_cnt
//   8256    : int   flags[MAXFLAG]       (32768)
//   41024   : u64   slots[MAXFLAG]       (65536)
//   106560  : float part[4][NBLK]        (16384)
//   122944  : char  kfrag[128*4096]      (524288)
//   647296  : float kT[64][2048]         (524288, optional)
#define WS_K2_OFF   0
#define WS_CNT_OFF  8192
#define WS_FLAG_OFF 8256
#define WS_SLOT_OFF 41024
#define WS_PART_OFF 106560
#define WS_KF_OFF   122944
#define WS_KT_OFF   647296
#define WS_KT_END   (WS_KT_OFF + (size_t)WDIM * KBINS * 4)

typedef __attribute__((ext_vector_type(8))) short bf16x8;
typedef __attribute__((ext_vector_type(4))) float f32x4;
typedef unsigned long long u64;

static __device__ __forceinline__ short f2bf(float v) {
  __hip_bfloat16 b = __float2bfloat16(v);
  return *reinterpret_cast<short*>(&b);
}
static __device__ __forceinline__ float bf2f(short s) {
  unsigned int u = ((unsigned int)(unsigned short)s) << 16;
  return __uint_as_float(u);
}

#define GLOAD_LDS(gsrc, ldst)                                            \
  __builtin_amdgcn_global_load_lds(                                      \
      (const __attribute__((address_space(1))) unsigned int*)(gsrc),     \
      (__attribute__((address_space(3))) unsigned int*)(ldst), 16, 0, 0)

// s_waitcnt immediates (gfx9): vmcnt[3:0] | expcnt<<4 | lgkmcnt<<8
#define WAIT_VM4 0x0F74
#define WAIT_VM0 0x0F70
#define SBAR() asm volatile("s_barrier" ::: "memory")

// prep: 1 block per 16-code tile. np-bit-exact k2 + fragment-ordered split-bf16
// codebook + optional kT transpose + ws init.
__global__ void prep_kernel(const float* __restrict__ kg, float* __restrict__ k2,
                            char* __restrict__ kfrag, float* __restrict__ kT,
                            int* __restrict__ cnt, u64* __restrict__ slots) {
  __shared__ float skc[16 * 65];
  const int tid  = threadIdx.x;
  const int tile = blockIdx.x;           // 0..127
  const int c0   = tile * 16;
  if (tile == 0 && tid == 0) *cnt = 0;
  if (tid < 64) slots[tile * 64 + tid] = ~0ULL;
  {
    const float4* g4 = (const float4*)(kg + (size_t)c0 * WDIM);
    int code = tid >> 4, w = (tid & 15) * 4;
    *(float4*)&skc[code * 65 + w] = g4[tid];
  }
  __syncthreads();
  if (tid < 16) {   // np-bit-exact k2 (8-accumulator pairwise)
    const float* kr = &skc[tid * 65];
    float r[8];
#pragma unroll
    for (int l = 0; l < 8; ++l) r[l] = __fmul_rn(kr[l], kr[l]);
    for (int i = 8; i < WDIM; i += 8) {
#pragma unroll
      for (int l = 0; l < 8; ++l)
        r[l] = __fadd_rn(r[l], __fmul_rn(kr[i + l], kr[i + l]));
    }
    k2[c0 + tid] = __fadd_rn(__fadd_rn(__fadd_rn(r[0], r[1]), __fadd_rn(r[2], r[3])),
                             __fadd_rn(__fadd_rn(r[4], r[5]), __fadd_rn(r[6], r[7])));
  }
  if (kT) {   // transposed copy for coalesced recheck reads (bit-exact values)
    const int code = tid & 15;
#pragma unroll
    for (int j = 0; j < 4; ++j) {
      int w = (tid >> 4) + 16 * j;
      kT[(size_t)w * KBINS + c0 + code] = skc[code * 65 + w];
    }
  }
  {
    const int sub  = tid >> 6;           // 0..3
    const int lane = tid & 63;
    const int lcol = lane & 15;
    const int quad = lane >> 4;
    const float* src = &skc[lcol * 65 + (sub & 1) * 32 + quad * 8];
    const bool lo = (sub >= 2);
    short tmp[8];
#pragma unroll
    for (int i = 0; i < 8; ++i) {
      float v = src[i];
      short h = f2bf(v);
      tmp[i] = lo ? f2bf(v - bf2f(h)) : h;
    }
    char* dst = kfrag + (size_t)tile * 4096 + sub * 1024 + lane * 16;
    *(bf16x8*)dst = *(const bf16x8*)tmp;
  }
}

// main: R2-PROVEN split-bf16 MFMA scan (68.5 us measured). 256 thr = 4 waves
// x 16 rows; shared 3-slot ring filled by wave0 (async global_load_lds behind
// per-wave vmcnt literals); one raw s_barrier per 16-code step.
// LDS = ring 12288 + k2f 8192 = 20480 -> grid-capped 4 blocks/CU.
__launch_bounds__(256, 4)
__global__ void vq_mono(const float* __restrict__ x,
                        const float* __restrict__ kg,
                        const float* __restrict__ k2g,
                        const char* __restrict__ kfrag,
                        float* __restrict__ out,
                        float* __restrict__ part,
                        int* __restrict__ flag_cnt,
                        int* __restrict__ flags) {
  __shared__ __align__(16) char smem[20480];
  char*  kbuf = smem;
  float* k2f  = (float*)(smem + 12288);
  short* sxh = (short*)smem;
  short* sxl = (short*)(smem + 9216);
  float* kd  = (float*)smem;
  int*   sIdx      = (int*)  (smem + 18432);
  float* sPair     = (float*)(smem + 18688);
  int*   sFlagCnt  = (int*)  (smem + 18752);
  int*   sFlagBase = (int*)  (smem + 18756);
  int*   sFlagList = (int*)  (smem + 18760);

  const int tid  = threadIdx.x;
  const int blk  = blockIdx.x;
  const int row0 = blk * MT;
  const int n    = row0 >> 13;
  const int t0   = row0 & (TDIM - 1);

  const int r  = tid & 63;
  const int wh = tid >> 6;
  float x2p = 0.f, sxp = 0.f;
  const float* xb = x + (size_t)n * WDIM * TDIM + t0 + r;
#pragma unroll 8
  for (int i = 0; i < 16; ++i) {
    int w = 4 * i + wh;
    float v = xb[(size_t)w * TDIM];
    x2p = fmaf(v, v, x2p);
    sxp += v;
    short h = f2bf(v);
    sxh[r * XST + w] = h;
    sxl[r * XST + w] = f2bf(v - bf2f(h));
  }
  __syncthreads();

  const int wave = tid >> 6;
  const int lane = tid & 63;
  const int lcol = lane & 15;
  const int quad = lane >> 4;
  const int rA = wave * 16 + lcol;
  bf16x8 ah0 = *(const bf16x8*)&sxh[rA * XST + 0  + quad * 8];
  bf16x8 ah1 = *(const bf16x8*)&sxh[rA * XST + 32 + quad * 8];
  bf16x8 al0 = *(const bf16x8*)&sxl[rA * XST + 0  + quad * 8];
  bf16x8 al1 = *(const bf16x8*)&sxl[rA * XST + 32 + quad * 8];
  __syncthreads();

  float bd[4], b2[4];
  int   bi[4];
#pragma unroll
  for (int i = 0; i < 4; ++i) { bd[i] = 3.0e38f; b2[i] = 3.0e38f; bi[i] = 0; }

  const char* kfg = kfrag;

#define VQM_ISSUE(C, B)                                                      \
  if ((C) < 128) {                                                           \
    const char* s = kfg + (size_t)(C) * 4096 + (lane << 4);                  \
    char* d = kbuf + (B) * 4096;                                             \
    GLOAD_LDS(s, d);                                                         \
    GLOAD_LDS(s + 1024, d + 1024);                                           \
    GLOAD_LDS(s + 2048, d + 2048);                                           \
    GLOAD_LDS(s + 3072, d + 3072);                                           \
  }

  {
    const float4* k24 = (const float4*)k2g;
    *(float4*)&k2f[tid * 8]     = k24[tid * 2];
    *(float4*)&k2f[tid * 8 + 4] = k24[tid * 2 + 1];
  }
  if (wave == 0) {
    VQM_ISSUE(0, 0)
    VQM_ISSUE(1, 1)
  }
  asm volatile("s_waitcnt lgkmcnt(0)\n\ts_barrier" ::: "memory");

#define VQM_STEP(C, RB, PB, WAITIMM)                                         \
  {                                                                          \
    if (wave == 0) __builtin_amdgcn_s_waitcnt(WAITIMM);                      \
    SBAR();                                                                  \
    const char* tb = kbuf + (RB) * 4096;                                     \
    bf16x8 bh0 = *(const bf16x8*)(tb + 0    + (lane << 4));                  \
    bf16x8 bh1 = *(const bf16x8*)(tb + 1024 + (lane << 4));                  \
    bf16x8 bl0 = *(const bf16x8*)(tb + 2048 + (lane << 4));                  \
    bf16x8 bl1 = *(const bf16x8*)(tb + 3072 + (lane << 4));                  \
    float k2c = k2f[(C) * 16 + lcol];                                        \
    if (wave == 0) { VQM_ISSUE((C) + 2, PB) }                                \
    f32x4 p = {0.f, 0.f, 0.f, 0.f};                                          \
    p = __builtin_amdgcn_mfma_f32_16x16x32_bf16(ah0, bh0, p, 0, 0, 0);       \
    p = __builtin_amdgcn_mfma_f32_16x16x32_bf16(ah1, bh1, p, 0, 0, 0);       \
    p = __builtin_amdgcn_mfma_f32_16x16x32_bf16(ah0, bl0, p, 0, 0, 0);       \
    p = __builtin_amdgcn_mfma_f32_16x16x32_bf16(ah1, bl1, p, 0, 0, 0);       \
    p = __builtin_amdgcn_mfma_f32_16x16x32_bf16(al0, bh0, p, 0, 0, 0);       \
    p = __builtin_amdgcn_mfma_f32_16x16x32_bf16(al1, bh1, p, 0, 0, 0);       \
    const int code = (C) * 16 + lcol;                                        \
    _Pragma("unroll")                                                        \
    for (int i = 0; i < 4; ++i) {                                            \
      float d0 = fmaf(-2.f, p[i], k2c);                                      \
      float nb2 = __builtin_amdgcn_fmed3f(bd[i], d0, b2[i]);                 \
      bool lt0 = d0 < bd[i];                                                 \
      bd[i] = lt0 ? d0 : bd[i];                                              \
      bi[i] = lt0 ? code : bi[i];                                            \
      b2[i] = nb2;                                                           \
    }                                                                        \
  }

  for (int c = 0; c < 126; c += 3) {
    VQM_STEP(c,     0, 2, WAIT_VM4)
    VQM_STEP(c + 1, 1, 0, WAIT_VM4)
    VQM_STEP(c + 2, 2, 1, WAIT_VM4)
  }
  VQM_STEP(126, 0, 2, WAIT_VM4)
  VQM_STEP(127, 1, 0, WAIT_VM0)
#undef VQM_STEP
#undef VQM_ISSUE

#pragma unroll
  for (int m = 1; m < 16; m <<= 1) {
#pragma unroll
    for (int i = 0; i < 4; ++i) {
      float od  = __shfl_xor(bd[i], m, 64);
      float od2 = __shfl_xor(b2[i], m, 64);
      int   oi  = __shfl_xor(bi[i], m, 64);
      float nb2 = fminf(fminf(b2[i], od2), fmaxf(bd[i], od));
      bool take = (od < bd[i]) || (od == bd[i] && oi < bi[i]);
      bd[i] = take ? od : bd[i];
      bi[i] = take ? oi : bi[i];
      b2[i] = nb2;
    }
  }

  __syncthreads();
  if (tid == 0) *sFlagCnt = 0;
  __syncthreads();

  float fit_p = 0.f;
  if (lcol == 0) {
#pragma unroll
    for (int i = 0; i < 4; ++i) {
      int rloc = wave * 16 + quad * 4 + i;
      int rowg = row0 + rloc;
      out[XL_OFF + rowg] = (float)bi[i];
      sIdx[rloc] = bi[i];
      fit_p += bd[i];
      if (b2[i] - bd[i] < TAU) {
        int slot = atomicAdd(sFlagCnt, 1);
        sFlagList[slot] = rowg;
      }
    }
  }
  __syncthreads();

  int nloc = *sFlagCnt;
  if (tid == 0 && nloc > 0) *sFlagBase = atomicAdd(flag_cnt, nloc);
  __syncthreads();
  if (tid < nloc) {
    int gs = *sFlagBase + tid;
    if (gs < MAXFLAG) flags[gs] = sFlagList[tid];
  }

  {
    int rr = tid >> 2, q4 = tid & 3;
    const float4* kr4 = (const float4*)(kg + (size_t)sIdx[rr] * WDIM) + q4 * 4;
    float4* dst = (float4*)&kd[rr * 68 + q4 * 16];
#pragma unroll
    for (int j = 0; j < 4; ++j) dst[j] = kr4[j];
  }
  __syncthreads();

  float commit_p = 0.f;
  float* xdb = out + XD_OFF + (size_t)n * WDIM * TDIM + t0 + r;
#pragma unroll 8
  for (int i = 0; i < 16; ++i) {
    int w = 4 * i + wh;
    float xvv = xb[(size_t)w * TDIM];
    float kvv = kd[r * 68 + w];
    float df = kvv - xvv;
    commit_p = fmaf(df, df, commit_p);
    xdb[(size_t)w * TDIM] = kvv;
  }

  float v0 = sxp, v1 = x2p, v2 = commit_p, v3 = fit_p;
#pragma unroll
  for (int off = 32; off > 0; off >>= 1) {
    v0 += __shfl_down(v0, off, 64);
    v1 += __shfl_down(v1, off, 64);
    v2 += __shfl_down(v2, off, 64);
    v3 += __shfl_down(v3, off, 64);
  }
  if (lane == 0) {
    sPair[wave * 4 + 0] = v0;
    sPair[wave * 4 + 1] = v1;
    sPair[wave * 4 + 2] = v2;
    sPair[wave * 4 + 3] = v3;
  }
  __syncthreads();
  if (tid == 0) {
    float x2sum = sPair[1] + sPair[5] + sPair[9] + sPair[13];
    part[0 * NBLK + blk] = sPair[0] + sPair[4] + sPair[8] + sPair[12];
    part[1 * NBLK + blk] = x2sum;
    part[2 * NBLK + blk] = sPair[2] + sPair[6] + sPair[10] + sPair[14];
    part[3 * NBLK + blk] = (sPair[3] + sPair[7] + sPair[11] + sPair[15]) + x2sum;
  }
}

// recheck pass 1 (REBUILT for 16x less codebook traffic): one block per 16
// flagged rows. Per 256-code chunk each thread caches ITS code's 64 coeffs
// in registers (kreg, coalesced via kT; static w-indexing only), then sweeps
// the 16 rows from LDS (broadcast). Per-(row,code) fmaf chain, d-combination,
// u64 key, and pairwise x2 are byte-identical to the proven bit-exact form.
__launch_bounds__(256, 2)
__global__ void recheck_scan(const float* __restrict__ x,
                             const float* __restrict__ kg,
                             const float* __restrict__ kT,
                             const float* __restrict__ k2g,
                             const int* __restrict__ flag_cnt,
                             const int* __restrict__ flags,
                             u64* __restrict__ slots) {
  __shared__ float xr[RPB][68];
  __shared__ float sx2[RPB];
  __shared__ u64   bestL[RPB];
  const int tid = threadIdx.x;
  int nf = *flag_cnt;
  if (nf > MAXFLAG) nf = MAXFLAG;
  const int fi0 = blockIdx.x * RPB;
  if (fi0 >= nf) return;
  const int nr = min(RPB, nf - fi0);

  // stage x rows: 16 rows x 16 threads x 4 w
  {
    int rr = tid >> 4;
    int wq = (tid & 15) * 4;
    if (rr < nr) {
      int row = flags[fi0 + rr];
      int n = row >> 13, t = row & (TDIM - 1);
      const float* xp = x + (size_t)n * WDIM * TDIM + t;
#pragma unroll
      for (int u = 0; u < 4; ++u)
        xr[rr][wq + u] = xp[(size_t)(wq + u) * TDIM];
    } else if (rr < RPB) {
#pragma unroll
      for (int u = 0; u < 4; ++u) xr[rr][wq + u] = 0.f;
    }
  }
  if (tid < RPB) bestL[tid] = ~0ULL;
  __syncthreads();
  if (tid < RPB) {   // np-pairwise x2 (bit-exact chain), one thread per row
    const float* sxp = xr[tid];
    float r8[8];
#pragma unroll
    for (int l = 0; l < 8; ++l) r8[l] = __fmul_rn(sxp[l], sxp[l]);
    for (int i = 8; i < WDIM; i += 8) {
#pragma unroll
      for (int l = 0; l < 8; ++l)
        r8[l] = __fadd_rn(r8[l], __fmul_rn(sxp[i + l], sxp[i + l]));
    }
    sx2[tid] = __fadd_rn(__fadd_rn(__fadd_rn(r8[0], r8[1]), __fadd_rn(r8[2], r8[3])),
                         __fadd_rn(__fadd_rn(r8[4], r8[5]), __fadd_rn(r8[6], r8[7])));
  }
  __syncthreads();

  for (int j0 = 0; j0 < KBINS; j0 += 256) {
    const int j = j0 + tid;
    float kreg[WDIM];
    if (kT) {
#pragma unroll
      for (int w = 0; w < WDIM; ++w) kreg[w] = kT[(size_t)w * KBINS + j];
    } else {
      const float* kr = kg + (size_t)j * WDIM;
#pragma unroll
      for (int w = 0; w < WDIM; ++w) kreg[w] = kr[w];
    }
    const float k2j = k2g[j];
#pragma unroll 2
    for (int rr = 0; rr < RPB; ++rr) {
      float c = 0.f;
#pragma unroll
      for (int w = 0; w < WDIM; ++w)
        c = __fmaf_rn(xr[rr][w], kreg[w], c);
      float d = __fadd_rn(__fsub_rn(sx2[rr], __fmul_rn(2.0f, c)), k2j);
      u64 key = ((u64)__float_as_uint(d) << 32) | (unsigned)j;
#pragma unroll
      for (int off = 32; off > 0; off >>= 1) {
        u64 o = __shfl_down((unsigned long long)key, off, 64);
        if (o < key) key = o;
      }
      if ((tid & 63) == 0) atomicMin(&bestL[rr], key);
    }
  }
  __syncthreads();
  if (tid < nr) atomicMin(&slots[fi0 + tid], bestL[tid]);
}

// recheck pass 2: persistent write-back.
__global__ void recheck_write(const float* __restrict__ kg,
                              const int* __restrict__ flag_cnt,
                              const int* __restrict__ flags,
                              const u64* __restrict__ slots,
                              float* __restrict__ out) {
  int nf = *flag_cnt;
  if (nf > MAXFLAG) nf = MAXFLAG;
  const int w = threadIdx.x;
  for (int fi = blockIdx.x; fi < nf; fi += 256) {
    const int row = flags[fi];
    const int n = row >> 13;
    const int t = row & (TDIM - 1);
    const int j = (int)(slots[fi] & 0xFFFFFFFFULL);
    if (w == 0) out[XL_OFF + row] = (float)j;
    out[XD_OFF + (size_t)n * WDIM * TDIM + (size_t)w * TDIM + t] = kg[(size_t)j * WDIM + w];
  }
}

// finalize: sum per-block partials (fp64) + emit the 3 scalars.
__global__ void finalize_kernel(const float* __restrict__ part, float* __restrict__ out) {
  __shared__ double sred[4][64];
  const int tid = threadIdx.x;     // 256
  const int lane = tid & 63;
  const int wv = tid >> 6;
  double a[4] = {0.0, 0.0, 0.0, 0.0};
  for (int i = tid; i < NBLK; i += 256) {
#pragma unroll
    for (int q = 0; q < 4; ++q) a[q] += (double)part[q * NBLK + i];
  }
#pragma unroll
  for (int off = 32; off > 0; off >>= 1) {
#pragma unroll
    for (int q = 0; q < 4; ++q)
      a[q] += __shfl_down(a[q], off, 64);
  }
  if (lane == 0) {
#pragma unroll
    for (int q = 0; q < 4; ++q) sred[q][wv] = a[q];
  }
  __syncthreads();
  if (tid == 0) {
    double s0 = 0, s1 = 0, s2 = 0, s3 = 0;
#pragma unroll
    for (int wv2 = 0; wv2 < 4; ++wv2) {
      s0 += sred[0][wv2]; s1 += sred[1][wv2];
      s2 += sred[2][wv2]; s3 += sred[3][wv2];
    }
    double size = (double)XSIZE;
    double commit = s2 / size;
    double fit = s3 / (double)NROWS;
    double mean = s0 / size;
    double var = s1 / size - mean * mean;
    if (var < 0.0) var = 0.0;
    out[SCAL_OFF + 0] = (float)commit;
    out[SCAL_OFF + 1] = (float)fit;
    out[SCAL_OFF + 2] = (float)sqrt(var);
  }
}

extern "C" void kernel_launch(void* const* d_in, const int* in_sizes, int n_in,
                              void* d_out, int out_size, void* d_ws, size_t ws_size,
                              hipStream_t stream) {
  const float* x = (const float*)d_in[0];
  const float* kg = (const float*)d_in[1];
  float* out = (float*)d_out;
  float* k2   = (float*)((char*)d_ws + WS_K2_OFF);
  int* cnt    = (int*)((char*)d_ws + WS_CNT_OFF);
  int* flags  = (int*)((char*)d_ws + WS_FLAG_OFF);
  u64* slots  = (u64*)((char*)d_ws + WS_SLOT_OFF);
  float* part = (float*)((char*)d_ws + WS_PART_OFF);
  char* kfrag = (char*)d_ws + WS_KF_OFF;
  float* kT   = (ws_size >= WS_KT_END) ? (float*)((char*)d_ws + WS_KT_OFF) : nullptr;

  hipLaunchKernelGGL(prep_kernel, dim3(KBINS / 16), dim3(256), 0, stream,
                     kg, k2, kfrag, kT, cnt, slots);
  hipLaunchKernelGGL(vq_mono, dim3(NBLK), dim3(256), 0, stream,
                     x, kg, k2, kfrag, out, part, cnt, flags);
  hipLaunchKernelGGL(recheck_scan, dim3(MAXFLAG / RPB), dim3(256), 0, stream,
                     x, kg, kT, k2, cnt, flags, slots);
  hipLaunchKernelGGL(recheck_write, dim3(256), dim3(WDIM), 0, stream,
                     kg, cnt, flags, slots, out);
  hipLaunchKernelGGL(finalize_kernel, dim3(1), dim3(256), 0, stream, part, out);
}

// Round 9
// 173.854 us; speedup vs baseline: 1.4766x; 1.3135x over previous
//
#include <hip/hip_runtime.h>
#include <hip/hip_bf16.h>
#include <math.h>

#define N_BATCH 8
#define WDIM 64
#define TDIM 8192
#define KBINS 2048
#define NROWS (N_BATCH * TDIM)          // 65536
#define XSIZE (N_BATCH * WDIM * TDIM)   // 4194304
#define XL_OFF 0
#define XD_OFF NROWS
#define SCAL_OFF (NROWS + XSIZE)

#define MT 64                           // rows per block
#define XST 72                          // bf16 LDS x row stride
#define TAU 0.05f
#define MAXFLAG 8192
#define NBLK (NROWS / MT)               // 1024

// ws layout (bytes):
//   0       : float k2[KBINS]            (8192)
//   8192    : int   flag_cnt
//   8256    : int   flags[MAXFLAG]       (32768)
//   41024   : u64   slots[MAXFLAG]       (65536)
//   106560  : float part[4][NBLK]        (16384)
//   122944  : char  kfrag[128*4096]      (524288)
//   647296  : float kT[64][2048]         (524288, optional)
//   1171584 : float xf[MAXFLAG][64]      (2097152, optional -> coalesced recheck)
#define WS_K2_OFF   0
#define WS_CNT_OFF  8192
#define WS_FLAG_OFF 8256
#define WS_SLOT_OFF 41024
#define WS_PART_OFF 106560
#define WS_KF_OFF   122944
#define WS_KT_OFF   647296
#define WS_KT_END   (WS_KT_OFF + (size_t)WDIM * KBINS * 4)
#define WS_XF_OFF   WS_KT_END
#define WS_XF_END   (WS_XF_OFF + (size_t)MAXFLAG * WDIM * 4)

typedef __attribute__((ext_vector_type(8))) short bf16x8;
typedef __attribute__((ext_vector_type(4))) float f32x4;
typedef unsigned long long u64;

static __device__ __forceinline__ short f2bf(float v) {
  __hip_bfloat16 b = __float2bfloat16(v);
  return *reinterpret_cast<short*>(&b);
}
static __device__ __forceinline__ float bf2f(short s) {
  unsigned int u = ((unsigned int)(unsigned short)s) << 16;
  return __uint_as_float(u);
}

#define GLOAD_LDS(gsrc, ldst)                                            \
  __builtin_amdgcn_global_load_lds(                                      \
      (const __attribute__((address_space(1))) unsigned int*)(gsrc),     \
      (__attribute__((address_space(3))) unsigned int*)(ldst), 16, 0, 0)

// s_waitcnt immediates (gfx9): vmcnt[3:0] | expcnt<<4 | lgkmcnt<<8
#define WAIT_VM4 0x0F74
#define WAIT_VM0 0x0F70
#define SBAR() asm volatile("s_barrier" ::: "memory")

// prep: 1 block per 16-code tile. np-bit-exact k2 + fragment-ordered split-bf16
// codebook + optional kT transpose + ws init.
__global__ void prep_kernel(const float* __restrict__ kg, float* __restrict__ k2,
                            char* __restrict__ kfrag, float* __restrict__ kT,
                            int* __restrict__ cnt, u64* __restrict__ slots) {
  __shared__ float skc[16 * 65];
  const int tid  = threadIdx.x;
  const int tile = blockIdx.x;           // 0..127
  const int c0   = tile * 16;
  if (tile == 0 && tid == 0) *cnt = 0;
  if (tid < 64) slots[tile * 64 + tid] = ~0ULL;
  {
    const float4* g4 = (const float4*)(kg + (size_t)c0 * WDIM);
    int code = tid >> 4, w = (tid & 15) * 4;
    *(float4*)&skc[code * 65 + w] = g4[tid];
  }
  __syncthreads();
  if (tid < 16) {   // np-bit-exact k2 (8-accumulator pairwise)
    const float* kr = &skc[tid * 65];
    float r[8];
#pragma unroll
    for (int l = 0; l < 8; ++l) r[l] = __fmul_rn(kr[l], kr[l]);
    for (int i = 8; i < WDIM; i += 8) {
#pragma unroll
      for (int l = 0; l < 8; ++l)
        r[l] = __fadd_rn(r[l], __fmul_rn(kr[i + l], kr[i + l]));
    }
    k2[c0 + tid] = __fadd_rn(__fadd_rn(__fadd_rn(r[0], r[1]), __fadd_rn(r[2], r[3])),
                             __fadd_rn(__fadd_rn(r[4], r[5]), __fadd_rn(r[6], r[7])));
  }
  if (kT) {   // transposed copy for coalesced recheck reads (bit-exact values)
    const int code = tid & 15;
#pragma unroll
    for (int j = 0; j < 4; ++j) {
      int w = (tid >> 4) + 16 * j;
      kT[(size_t)w * KBINS + c0 + code] = skc[code * 65 + w];
    }
  }
  {
    const int sub  = tid >> 6;           // 0..3
    const int lane = tid & 63;
    const int lcol = lane & 15;
    const int quad = lane >> 4;
    const float* src = &skc[lcol * 65 + (sub & 1) * 32 + quad * 8];
    const bool lo = (sub >= 2);
    short tmp[8];
#pragma unroll
    for (int i = 0; i < 8; ++i) {
      float v = src[i];
      short h = f2bf(v);
      tmp[i] = lo ? f2bf(v - bf2f(h)) : h;
    }
    char* dst = kfrag + (size_t)tile * 4096 + sub * 1024 + lane * 16;
    *(bf16x8*)dst = *(const bf16x8*)tmp;
  }
}

// main: R2-PROVEN split-bf16 MFMA scan (68.5 us measured). 256 thr = 4 waves
// x 16 rows; shared 3-slot ring filled by wave0 (async global_load_lds behind
// per-wave vmcnt literals); one raw s_barrier per 16-code step.
// LDS = ring 12288 + k2f 8192 = 20480 -> grid-capped 4 blocks/CU.
// NEW: epilogue exports each flagged row's fp32 x values to compact xf[slot]
// so recheck reads them coalesced instead of 64 scattered cache lines.
__launch_bounds__(256, 4)
__global__ void vq_mono(const float* __restrict__ x,
                        const float* __restrict__ kg,
                        const float* __restrict__ k2g,
                        const char* __restrict__ kfrag,
                        float* __restrict__ out,
                        float* __restrict__ part,
                        int* __restrict__ flag_cnt,
                        int* __restrict__ flags,
                        float* __restrict__ xf) {
  __shared__ __align__(16) char smem[20480];
  char*  kbuf = smem;
  float* k2f  = (float*)(smem + 12288);
  short* sxh = (short*)smem;
  short* sxl = (short*)(smem + 9216);
  float* kd  = (float*)smem;
  int*   sIdx      = (int*)  (smem + 18432);
  float* sPair     = (float*)(smem + 18688);
  int*   sFlagCnt  = (int*)  (smem + 18752);
  int*   sFlagBase = (int*)  (smem + 18756);
  int*   sFlagList = (int*)  (smem + 18760);

  const int tid  = threadIdx.x;
  const int blk  = blockIdx.x;
  const int row0 = blk * MT;
  const int n    = row0 >> 13;
  const int t0   = row0 & (TDIM - 1);

  const int r  = tid & 63;
  const int wh = tid >> 6;
  float x2p = 0.f, sxp = 0.f;
  const float* xb = x + (size_t)n * WDIM * TDIM + t0 + r;
#pragma unroll 8
  for (int i = 0; i < 16; ++i) {
    int w = 4 * i + wh;
    float v = xb[(size_t)w * TDIM];
    x2p = fmaf(v, v, x2p);
    sxp += v;
    short h = f2bf(v);
    sxh[r * XST + w] = h;
    sxl[r * XST + w] = f2bf(v - bf2f(h));
  }
  __syncthreads();

  const int wave = tid >> 6;
  const int lane = tid & 63;
  const int lcol = lane & 15;
  const int quad = lane >> 4;
  const int rA = wave * 16 + lcol;
  bf16x8 ah0 = *(const bf16x8*)&sxh[rA * XST + 0  + quad * 8];
  bf16x8 ah1 = *(const bf16x8*)&sxh[rA * XST + 32 + quad * 8];
  bf16x8 al0 = *(const bf16x8*)&sxl[rA * XST + 0  + quad * 8];
  bf16x8 al1 = *(const bf16x8*)&sxl[rA * XST + 32 + quad * 8];
  __syncthreads();

  float bd[4], b2[4];
  int   bi[4];
#pragma unroll
  for (int i = 0; i < 4; ++i) { bd[i] = 3.0e38f; b2[i] = 3.0e38f; bi[i] = 0; }

  const char* kfg = kfrag;

#define VQM_ISSUE(C, B)                                                      \
  if ((C) < 128) {                                                           \
    const char* s = kfg + (size_t)(C) * 4096 + (lane << 4);                  \
    char* d = kbuf + (B) * 4096;                                             \
    GLOAD_LDS(s, d);                                                         \
    GLOAD_LDS(s + 1024, d + 1024);                                           \
    GLOAD_LDS(s + 2048, d + 2048);                                           \
    GLOAD_LDS(s + 3072, d + 3072);                                           \
  }

  {
    const float4* k24 = (const float4*)k2g;
    *(float4*)&k2f[tid * 8]     = k24[tid * 2];
    *(float4*)&k2f[tid * 8 + 4] = k24[tid * 2 + 1];
  }
  if (wave == 0) {
    VQM_ISSUE(0, 0)
    VQM_ISSUE(1, 1)
  }
  asm volatile("s_waitcnt lgkmcnt(0)\n\ts_barrier" ::: "memory");

#define VQM_STEP(C, RB, PB, WAITIMM)                                         \
  {                                                                          \
    if (wave == 0) __builtin_amdgcn_s_waitcnt(WAITIMM);                      \
    SBAR();                                                                  \
    const char* tb = kbuf + (RB) * 4096;                                     \
    bf16x8 bh0 = *(const bf16x8*)(tb + 0    + (lane << 4));                  \
    bf16x8 bh1 = *(const bf16x8*)(tb + 1024 + (lane << 4));                  \
    bf16x8 bl0 = *(const bf16x8*)(tb + 2048 + (lane << 4));                  \
    bf16x8 bl1 = *(const bf16x8*)(tb + 3072 + (lane << 4));                  \
    float k2c = k2f[(C) * 16 + lcol];                                        \
    if (wave == 0) { VQM_ISSUE((C) + 2, PB) }                                \
    f32x4 p = {0.f, 0.f, 0.f, 0.f};                                          \
    p = __builtin_amdgcn_mfma_f32_16x16x32_bf16(ah0, bh0, p, 0, 0, 0);       \
    p = __builtin_amdgcn_mfma_f32_16x16x32_bf16(ah1, bh1, p, 0, 0, 0);       \
    p = __builtin_amdgcn_mfma_f32_16x16x32_bf16(ah0, bl0, p, 0, 0, 0);       \
    p = __builtin_amdgcn_mfma_f32_16x16x32_bf16(ah1, bl1, p, 0, 0, 0);       \
    p = __builtin_amdgcn_mfma_f32_16x16x32_bf16(al0, bh0, p, 0, 0, 0);       \
    p = __builtin_amdgcn_mfma_f32_16x16x32_bf16(al1, bh1, p, 0, 0, 0);       \
    const int code = (C) * 16 + lcol;                                        \
    _Pragma("unroll")                                                        \
    for (int i = 0; i < 4; ++i) {                                            \
      float d0 = fmaf(-2.f, p[i], k2c);                                      \
      float nb2 = __builtin_amdgcn_fmed3f(bd[i], d0, b2[i]);                 \
      bool lt0 = d0 < bd[i];                                                 \
      bd[i] = lt0 ? d0 : bd[i];                                              \
      bi[i] = lt0 ? code : bi[i];                                            \
      b2[i] = nb2;                                                           \
    }                                                                        \
  }

  for (int c = 0; c < 126; c += 3) {
    VQM_STEP(c,     0, 2, WAIT_VM4)
    VQM_STEP(c + 1, 1, 0, WAIT_VM4)
    VQM_STEP(c + 2, 2, 1, WAIT_VM4)
  }
  VQM_STEP(126, 0, 2, WAIT_VM4)
  VQM_STEP(127, 1, 0, WAIT_VM0)
#undef VQM_STEP
#undef VQM_ISSUE

#pragma unroll
  for (int m = 1; m < 16; m <<= 1) {
#pragma unroll
    for (int i = 0; i < 4; ++i) {
      float od  = __shfl_xor(bd[i], m, 64);
      float od2 = __shfl_xor(b2[i], m, 64);
      int   oi  = __shfl_xor(bi[i], m, 64);
      float nb2 = fminf(fminf(b2[i], od2), fmaxf(bd[i], od));
      bool take = (od < bd[i]) || (od == bd[i] && oi < bi[i]);
      bd[i] = take ? od : bd[i];
      bi[i] = take ? oi : bi[i];
      b2[i] = nb2;
    }
  }

  __syncthreads();
  if (tid == 0) *sFlagCnt = 0;
  __syncthreads();

  float fit_p = 0.f;
  if (lcol == 0) {
#pragma unroll
    for (int i = 0; i < 4; ++i) {
      int rloc = wave * 16 + quad * 4 + i;
      int rowg = row0 + rloc;
      out[XL_OFF + rowg] = (float)bi[i];
      sIdx[rloc] = bi[i];
      fit_p += bd[i];
      if (b2[i] - bd[i] < TAU) {
        int slot = atomicAdd(sFlagCnt, 1);
        sFlagList[slot] = rowg;
      }
    }
  }
  __syncthreads();

  int nloc = *sFlagCnt;
  if (tid == 0 && nloc > 0) *sFlagBase = atomicAdd(flag_cnt, nloc);
  __syncthreads();
  if (tid < nloc) {
    int gs = *sFlagBase + tid;
    if (gs < MAXFLAG) flags[gs] = sFlagList[tid];
  }

  // xf export: for each flagged row, the 4 threads holding it (r == rloc,
  // wh = 0..3) write its 64 fp32 x values to the compact xf[slot] row
  // (raw re-reads, L2-warm; byte-identical values to what np uses).
  if (xf) {
    for (int i = 0; i < nloc; ++i) {
      int gs = *sFlagBase + i;
      if (gs >= MAXFLAG) break;
      int rloc = sFlagList[i] - row0;
      if (r == rloc) {
#pragma unroll
        for (int ii = 0; ii < 16; ++ii)
          xf[(size_t)gs * WDIM + 4 * ii + wh] = xb[(size_t)(4 * ii + wh) * TDIM];
      }
    }
  }

  {
    int rr = tid >> 2, q4 = tid & 3;
    const float4* kr4 = (const float4*)(kg + (size_t)sIdx[rr] * WDIM) + q4 * 4;
    float4* dst = (float4*)&kd[rr * 68 + q4 * 16];
#pragma unroll
    for (int j = 0; j < 4; ++j) dst[j] = kr4[j];
  }
  __syncthreads();

  float commit_p = 0.f;
  float* xdb = out + XD_OFF + (size_t)n * WDIM * TDIM + t0 + r;
#pragma unroll 8
  for (int i = 0; i < 16; ++i) {
    int w = 4 * i + wh;
    float xvv = xb[(size_t)w * TDIM];
    float kvv = kd[r * 68 + w];
    float df = kvv - xvv;
    commit_p = fmaf(df, df, commit_p);
    xdb[(size_t)w * TDIM] = kvv;
  }

  float v0 = sxp, v1 = x2p, v2 = commit_p, v3 = fit_p;
#pragma unroll
  for (int off = 32; off > 0; off >>= 1) {
    v0 += __shfl_down(v0, off, 64);
    v1 += __shfl_down(v1, off, 64);
    v2 += __shfl_down(v2, off, 64);
    v3 += __shfl_down(v3, off, 64);
  }
  if (lane == 0) {
    sPair[wave * 4 + 0] = v0;
    sPair[wave * 4 + 1] = v1;
    sPair[wave * 4 + 2] = v2;
    sPair[wave * 4 + 3] = v3;
  }
  __syncthreads();
  if (tid == 0) {
    float x2sum = sPair[1] + sPair[5] + sPair[9] + sPair[13];
    part[0 * NBLK + blk] = sPair[0] + sPair[4] + sPair[8] + sPair[12];
    part[1 * NBLK + blk] = x2sum;
    part[2 * NBLK + blk] = sPair[2] + sPair[6] + sPair[10] + sPair[14];
    part[3 * NBLK + blk] = (sPair[3] + sPair[7] + sPair[11] + sPair[15]) + x2sum;
  }
}

// recheck pass 1 (REBUILT: one block per flagged row, x in REGISTERS).
// Row loaded coalesced from xf (fallback: scattered from x). x hoisted once
// into xreg[64] (static indices), then thread t sweeps codes {t+256s,
// t+1024+256s} s=0..3 -- two independent fmaf chains per iteration, kT
// streams coalesced + L2-resident. Per-(row,code) fmaf order, d-combination,
// u64 key, and pairwise x2 chain are byte-identical to the proven form.
__launch_bounds__(256, 2)
__global__ void recheck_scan(const float* __restrict__ x,
                             const float* __restrict__ xf,
                             const float* __restrict__ kg,
                             const float* __restrict__ kT,
                             const float* __restrict__ k2g,
                             const int* __restrict__ flag_cnt,
                             const int* __restrict__ flags,
                             u64* __restrict__ slots) {
  __shared__ float sx[WDIM];
  __shared__ float sx2s;
  __shared__ u64 swm[4];
  const int tid  = threadIdx.x;
  const int lane = tid & 63;
  const int wv   = tid >> 6;
  int nf = *flag_cnt;
  if (nf > MAXFLAG) nf = MAXFLAG;

  for (int fi = blockIdx.x; fi < nf; fi += 2048) {
    const int row = flags[fi];
    if (tid < WDIM) {
      if (xf) {
        sx[tid] = xf[(size_t)fi * WDIM + tid];            // coalesced 256B
      } else {
        int n = row >> 13, t = row & (TDIM - 1);
        sx[tid] = x[(size_t)n * WDIM * TDIM + (size_t)tid * TDIM + t];
      }
    }
    __syncthreads();
    if (tid == 0) {   // np-pairwise x2 (bit-exact chain)
      float r8[8];
#pragma unroll
      for (int l = 0; l < 8; ++l) r8[l] = __fmul_rn(sx[l], sx[l]);
      for (int i = 8; i < WDIM; i += 8) {
#pragma unroll
        for (int l = 0; l < 8; ++l)
          r8[l] = __fadd_rn(r8[l], __fmul_rn(sx[i + l], sx[i + l]));
      }
      sx2s = __fadd_rn(__fadd_rn(__fadd_rn(r8[0], r8[1]), __fadd_rn(r8[2], r8[3])),
                       __fadd_rn(__fadd_rn(r8[4], r8[5]), __fadd_rn(r8[6], r8[7])));
    }
    __syncthreads();

    float xreg[WDIM];       // hoist row to registers ONCE (static indexing)
#pragma unroll
    for (int w = 0; w < WDIM; ++w) xreg[w] = sx[w];
    const float sx2v = sx2s;

    u64 best = ~0ULL;
#pragma unroll 1
    for (int s = 0; s < 4; ++s) {
      const int j0 = s * 256 + tid;
      const int j1 = j0 + 1024;
      float c0 = 0.f, c1 = 0.f;
      if (kT) {
#pragma unroll
        for (int w = 0; w < WDIM; ++w) {
          c0 = __fmaf_rn(xreg[w], kT[(size_t)w * KBINS + j0], c0);
          c1 = __fmaf_rn(xreg[w], kT[(size_t)w * KBINS + j1], c1);
        }
      } else {
        const float* kr0 = kg + (size_t)j0 * WDIM;
        const float* kr1 = kg + (size_t)j1 * WDIM;
#pragma unroll
        for (int w = 0; w < WDIM; ++w) {
          c0 = __fmaf_rn(xreg[w], kr0[w], c0);
          c1 = __fmaf_rn(xreg[w], kr1[w], c1);
        }
      }
      float d0 = __fadd_rn(__fsub_rn(sx2v, __fmul_rn(2.0f, c0)), k2g[j0]);
      float d1 = __fadd_rn(__fsub_rn(sx2v, __fmul_rn(2.0f, c1)), k2g[j1]);
      u64 key0 = ((u64)__float_as_uint(d0) << 32) | (unsigned)j0;
      u64 key1 = ((u64)__float_as_uint(d1) << 32) | (unsigned)j1;
      if (key0 < best) best = key0;
      if (key1 < best) best = key1;
    }
#pragma unroll
    for (int off = 32; off > 0; off >>= 1) {
      u64 o = __shfl_down((unsigned long long)best, off, 64);
      if (o < best) best = o;
    }
    if (lane == 0) swm[wv] = best;
    __syncthreads();
    if (tid == 0) {
      u64 b = swm[0];
#pragma unroll
      for (int k = 1; k < 4; ++k) b = (swm[k] < b) ? swm[k] : b;
      atomicMin(&slots[fi], b);
    }
    __syncthreads();
  }
}

// recheck pass 2: persistent write-back.
__global__ void recheck_write(const float* __restrict__ kg,
                              const int* __restrict__ flag_cnt,
                              const int* __restrict__ flags,
                              const u64* __restrict__ slots,
                              float* __restrict__ out) {
  int nf = *flag_cnt;
  if (nf > MAXFLAG) nf = MAXFLAG;
  const int w = threadIdx.x;
  for (int fi = blockIdx.x; fi < nf; fi += 256) {
    const int row = flags[fi];
    const int n = row >> 13;
    const int t = row & (TDIM - 1);
    const int j = (int)(slots[fi] & 0xFFFFFFFFULL);
    if (w == 0) out[XL_OFF + row] = (float)j;
    out[XD_OFF + (size_t)n * WDIM * TDIM + (size_t)w * TDIM + t] = kg[(size_t)j * WDIM + w];
  }
}

// finalize: sum per-block partials (fp64) + emit the 3 scalars.
__global__ void finalize_kernel(const float* __restrict__ part, float* __restrict__ out) {
  __shared__ double sred[4][64];
  const int tid = threadIdx.x;     // 256
  const int lane = tid & 63;
  const int wv = tid >> 6;
  double a[4] = {0.0, 0.0, 0.0, 0.0};
  for (int i = tid; i < NBLK; i += 256) {
#pragma unroll
    for (int q = 0; q < 4; ++q) a[q] += (double)part[q * NBLK + i];
  }
#pragma unroll
  for (int off = 32; off > 0; off >>= 1) {
#pragma unroll
    for (int q = 0; q < 4; ++q)
      a[q] += __shfl_down(a[q], off, 64);
  }
  if (lane == 0) {
#pragma unroll
    for (int q = 0; q < 4; ++q) sred[q][wv] = a[q];
  }
  __syncthreads();
  if (tid == 0) {
    double s0 = 0, s1 = 0, s2 = 0, s3 = 0;
#pragma unroll
    for (int wv2 = 0; wv2 < 4; ++wv2) {
      s0 += sred[0][wv2]; s1 += sred[1][wv2];
      s2 += sred[2][wv2]; s3 += sred[3][wv2];
    }
    double size = (double)XSIZE;
    double commit = s2 / size;
    double fit = s3 / (double)NROWS;
    double mean = s0 / size;
    double var = s1 / size - mean * mean;
    if (var < 0.0) var = 0.0;
    out[SCAL_OFF + 0] = (float)commit;
    out[SCAL_OFF + 1] = (float)fit;
    out[SCAL_OFF + 2] = (float)sqrt(var);
  }
}

extern "C" void kernel_launch(void* const* d_in, const int* in_sizes, int n_in,
                              void* d_out, int out_size, void* d_ws, size_t ws_size,
                              hipStream_t stream) {
  const float* x = (const float*)d_in[0];
  const float* kg = (const float*)d_in[1];
  float* out = (float*)d_out;
  float* k2   = (float*)((char*)d_ws + WS_K2_OFF);
  int* cnt    = (int*)((char*)d_ws + WS_CNT_OFF);
  int* flags  = (int*)((char*)d_ws + WS_FLAG_OFF);
  u64* slots  = (u64*)((char*)d_ws + WS_SLOT_OFF);
  float* part = (float*)((char*)d_ws + WS_PART_OFF);
  char* kfrag = (char*)d_ws + WS_KF_OFF;
  float* kT   = (ws_size >= WS_KT_END) ? (float*)((char*)d_ws + WS_KT_OFF) : nullptr;
  float* xf   = (ws_size >= WS_XF_END) ? (float*)((char*)d_ws + WS_XF_OFF) : nullptr;

  hipLaunchKernelGGL(prep_kernel, dim3(KBINS / 16), dim3(256), 0, stream,
                     kg, k2, kfrag, kT, cnt, slots);
  hipLaunchKernelGGL(vq_mono, dim3(NBLK), dim3(256), 0, stream,
                     x, kg, k2, kfrag, out, part, cnt, flags, xf);
  hipLaunchKernelGGL(recheck_scan, dim3(2048), dim3(256), 0, stream,
                     x, xf, kg, kT, k2, cnt, flags, slots);
  hipLaunchKernelGGL(recheck_write, dim3(256), dim3(WDIM), 0, stream,
                     kg, cnt, flags, slots, out);
  hipLaunchKernelGGL(finalize_kernel, dim3(1), dim3(256), 0, stream, part, out);
}